// Round 1
// baseline (3197.123 us; speedup 1.0000x reference)
//
#include <hip/hip_runtime.h>

#define NN 100000
#define NE 1600000
// IN_F = HID = 128, OUT_F = 64

// ---------------- degree accumulation ----------------
__global__ __launch_bounds__(256) void deg_kernel(
    const int* __restrict__ src, const int* __restrict__ dst,
    float* __restrict__ degO, float* __restrict__ degI, int nE) {
  int i = blockIdx.x * blockDim.x + threadIdx.x;
  int stride = gridDim.x * blockDim.x;
  for (int e = i; e < nE; e += stride) {
    atomicAdd(&degO[src[e]], 1.0f);
    atomicAdd(&degI[dst[e]], 1.0f);
  }
}

// in-place: deg -> rsqrt(max(deg,1))
__global__ __launch_bounds__(256) void norm_kernel(
    float* __restrict__ ns, float* __restrict__ nd, int n) {
  int i = blockIdx.x * blockDim.x + threadIdx.x;
  if (i < n) {
    ns[i] = rsqrtf(fmaxf(ns[i], 1.0f));
    nd[i] = rsqrtf(fmaxf(nd[i], 1.0f));
  }
}

// ---------------- edge aggregation: out[dst] += x[src] * ns[src] ----------------
// one wave per edge, 2 floats per lane. out must be pre-zeroed.
__global__ __launch_bounds__(256) void agg_kernel(
    const float* __restrict__ x, const int* __restrict__ src,
    const int* __restrict__ dst, const float* __restrict__ ns,
    float* __restrict__ out, int nE) {
  int wid  = (blockIdx.x * blockDim.x + threadIdx.x) >> 6;
  int lane = threadIdx.x & 63;
  int nwaves = (gridDim.x * blockDim.x) >> 6;
  for (int e = wid; e < nE; e += nwaves) {
    int s = src[e];
    int d = dst[e];
    float sc = ns[s];
    float2 v = *reinterpret_cast<const float2*>(x + (size_t)s * 128 + lane * 2);
    float* o = out + (size_t)d * 128 + lane * 2;
    atomicAdd(o, v.x * sc);
    atomicAdd(o + 1, v.y * sc);
  }
}

// ---------------- C = (A * rowscale) @ W + bias ----------------
// A:[nrows,K] W:[K,COLS] C:[nrows,COLS]; TM rows per block, 256 threads.
template <int K, int COLS, int TM, bool RELU>
__global__ __launch_bounds__(256) void gemm_kernel(
    const float* __restrict__ A, const float* __restrict__ rowscale,
    const float* __restrict__ W, const float* __restrict__ bias,
    float* __restrict__ C) {
  constexpr int RG = 256 / COLS;   // row groups
  constexpr int RPT = TM / RG;     // rows per thread
  __shared__ float a_lds[TM * K];
  const int row0 = blockIdx.x * TM;
  const int tid = threadIdx.x;

  // stage A tile (scaled)
  constexpr int NV4 = TM * K / 4;
  for (int i = tid; i < NV4; i += 256) {
    int r = (i * 4) / K;
    float4 v = *reinterpret_cast<const float4*>(A + (size_t)(row0 + r) * K + (i * 4) % K);
    float sc = rowscale ? rowscale[row0 + r] : 1.0f;
    v.x *= sc; v.y *= sc; v.z *= sc; v.w *= sc;
    *reinterpret_cast<float4*>(&a_lds[i * 4]) = v;
  }
  __syncthreads();

  const int col = tid % COLS;
  const int rg = tid / COLS;
  float acc[RPT] = {};
  for (int k0 = 0; k0 < K; k0 += 4) {
    float w0 = W[(size_t)(k0 + 0) * COLS + col];
    float w1 = W[(size_t)(k0 + 1) * COLS + col];
    float w2 = W[(size_t)(k0 + 2) * COLS + col];
    float w3 = W[(size_t)(k0 + 3) * COLS + col];
#pragma unroll
    for (int j = 0; j < RPT; ++j) {
      int r = rg * RPT + j;
      float4 a = *reinterpret_cast<const float4*>(&a_lds[r * K + k0]);
      acc[j] = fmaf(a.x, w0, acc[j]);
      acc[j] = fmaf(a.y, w1, acc[j]);
      acc[j] = fmaf(a.z, w2, acc[j]);
      acc[j] = fmaf(a.w, w3, acc[j]);
    }
  }
  float bv = bias[col];
#pragma unroll
  for (int j = 0; j < RPT; ++j) {
    float v = acc[j] + bv;
    if (RELU) v = fmaxf(v, 0.0f);
    C[(size_t)(row0 + rg * RPT + j) * COLS + col] = v;
  }
}

// ---------------- fused MLP + proj ----------------
// H:[N,128] -> z=relu(H@W3+b3):[*,256] (LDS only) -> y=z@W4+b4:[*,64]
// -> out = max(eps, |y| * rsqrt(sum(y^2)))
__global__ __launch_bounds__(256) void mlp_kernel(
    const float* __restrict__ H, const float* __restrict__ W3,
    const float* __restrict__ b3, const float* __restrict__ W4,
    const float* __restrict__ b4, float* __restrict__ Out) {
  constexpr int TM = 32;
  __shared__ float h_lds[TM * 128];
  __shared__ float z_lds[TM * 256];
  const int row0 = blockIdx.x * TM;
  const int tid = threadIdx.x;

  // stage H tile
  for (int i = tid; i < TM * 128 / 4; i += 256) {
    *reinterpret_cast<float4*>(&h_lds[i * 4]) =
        *reinterpret_cast<const float4*>(H + (size_t)row0 * 128 + i * 4);
  }
  __syncthreads();

  // phase B: z = relu(H@W3 + b3); one col per thread (256 cols)
  {
    const int col = tid;
    float acc[TM] = {};
    for (int k0 = 0; k0 < 128; k0 += 4) {
      float w0 = W3[(size_t)(k0 + 0) * 256 + col];
      float w1 = W3[(size_t)(k0 + 1) * 256 + col];
      float w2 = W3[(size_t)(k0 + 2) * 256 + col];
      float w3v = W3[(size_t)(k0 + 3) * 256 + col];
#pragma unroll
      for (int r = 0; r < TM; ++r) {
        float4 a = *reinterpret_cast<const float4*>(&h_lds[r * 128 + k0]);
        acc[r] = fmaf(a.x, w0, acc[r]);
        acc[r] = fmaf(a.y, w1, acc[r]);
        acc[r] = fmaf(a.z, w2, acc[r]);
        acc[r] = fmaf(a.w, w3v, acc[r]);
      }
    }
    float bv = b3[col];
#pragma unroll
    for (int r = 0; r < TM; ++r)
      z_lds[r * 256 + col] = fmaxf(acc[r] + bv, 0.0f);
  }
  __syncthreads();

  // phase C: y = z@W4 + b4; col = tid%64, 4 row-groups of 8 rows
  const int col = tid % 64;
  const int rg = tid / 64;
  float yv[8];
  {
    float acc[8] = {};
    for (int k0 = 0; k0 < 256; k0 += 4) {
      float w0 = W4[(size_t)(k0 + 0) * 64 + col];
      float w1 = W4[(size_t)(k0 + 1) * 64 + col];
      float w2 = W4[(size_t)(k0 + 2) * 64 + col];
      float w3v = W4[(size_t)(k0 + 3) * 64 + col];
#pragma unroll
      for (int j = 0; j < 8; ++j) {
        int r = rg * 8 + j;
        float4 a = *reinterpret_cast<const float4*>(&z_lds[r * 256 + k0]);
        acc[j] = fmaf(a.x, w0, acc[j]);
        acc[j] = fmaf(a.y, w1, acc[j]);
        acc[j] = fmaf(a.z, w2, acc[j]);
        acc[j] = fmaf(a.w, w3v, acc[j]);
      }
    }
    float bv = b4[col];
#pragma unroll
    for (int j = 0; j < 8; ++j) yv[j] = acc[j] + bv;
  }

  // phase D: stash y into h_lds (reuse; 32*64 floats <= 32*128), then row-norm
#pragma unroll
  for (int j = 0; j < 8; ++j) h_lds[(rg * 8 + j) * 64 + col] = yv[j];
  __syncthreads();
  {
    const int r = tid / 8;       // row within tile
    const int seg = tid % 8;     // 8 floats per thread
    float ss = 0.0f;
#pragma unroll
    for (int j = 0; j < 8; ++j) {
      float v = h_lds[r * 64 + seg * 8 + j];
      ss = fmaf(v, v, ss);
    }
    ss += __shfl_xor(ss, 1);
    ss += __shfl_xor(ss, 2);
    ss += __shfl_xor(ss, 4);
    float rinv = rsqrtf(ss);
#pragma unroll
    for (int j = 0; j < 8; ++j) {
      float v = fabsf(h_lds[r * 64 + seg * 8 + j]) * rinv;
      Out[(size_t)(row0 + r) * 64 + seg * 8 + j] = fmaxf(1e-6f, v);
    }
  }
}

extern "C" void kernel_launch(void* const* d_in, const int* in_sizes, int n_in,
                              void* d_out, int out_size, void* d_ws, size_t ws_size,
                              hipStream_t stream) {
  const float* feat = (const float*)d_in[0];
  const int* src = (const int*)d_in[1];
  const int* dst = (const int*)d_in[2];
  const float* W1 = (const float*)d_in[3];
  const float* b1 = (const float*)d_in[4];
  const float* W2 = (const float*)d_in[5];
  const float* b2 = (const float*)d_in[6];
  const float* W3 = (const float*)d_in[7];
  const float* b3 = (const float*)d_in[8];
  const float* W4 = (const float*)d_in[9];
  const float* b4 = (const float*)d_in[10];
  float* out = (float*)d_out;

  char* ws = (char*)d_ws;
  float* ns = (float*)ws;                       // [N] norm_src
  float* nd = ns + NN;                          // [N] norm_dst
  // 2*NN*4 = 800000 bytes, already 256B-aligned
  float* bufA = (float*)(ws + 2 * (size_t)NN * 4);  // [N,128]
  float* bufB = bufA + (size_t)NN * 128;            // [N,128]

  // degrees -> norms
  hipMemsetAsync(ns, 0, 2 * (size_t)NN * 4, stream);
  deg_kernel<<<2048, 256, 0, stream>>>(src, dst, ns, nd, NE);
  norm_kernel<<<(NN + 255) / 256, 256, 0, stream>>>(ns, nd, NN);

  // layer 1: aggregate feat -> bufA; h1 = (bufA*nd)@W1+b1 -> bufB
  hipMemsetAsync(bufA, 0, (size_t)NN * 128 * 4, stream);
  agg_kernel<<<2048, 256, 0, stream>>>(feat, src, dst, ns, bufA, NE);
  gemm_kernel<128, 128, 32, false><<<NN / 32, 256, 0, stream>>>(bufA, nd, W1, b1, bufB);

  // layer 2: aggregate bufB -> bufA; h2 = (bufA*nd)@W2+b2 -> bufB
  hipMemsetAsync(bufA, 0, (size_t)NN * 128 * 4, stream);
  agg_kernel<<<2048, 256, 0, stream>>>(bufB, src, dst, ns, bufA, NE);
  gemm_kernel<128, 128, 32, false><<<NN / 32, 256, 0, stream>>>(bufA, nd, W2, b2, bufB);

  // fused MLP + proj -> out
  mlp_kernel<<<NN / 32, 256, 0, stream>>>(bufB, W3, b3, W4, b4, out);
}

// Round 2
// 872.488 us; speedup vs baseline: 3.6644x; 3.6644x over previous
//
#include <hip/hip_runtime.h>

#define NN 100000
#define NE 1600000
// IN_F = HID = 128, OUT_F = 64

// ---------------- int degree accumulation ----------------
__global__ __launch_bounds__(256) void degi_kernel(
    const int* __restrict__ src, const int* __restrict__ dst,
    int* __restrict__ degO, int* __restrict__ degI, int nE) {
  int i = blockIdx.x * blockDim.x + threadIdx.x;
  int stride = gridDim.x * blockDim.x;
  for (int e = i; e < nE; e += stride) {
    atomicAdd(&degO[src[e]], 1);
    atomicAdd(&degI[dst[e]], 1);
  }
}

__global__ __launch_bounds__(256) void normi_kernel(
    const int* __restrict__ degO, const int* __restrict__ degI,
    float* __restrict__ ns, float* __restrict__ nd, int n) {
  int i = blockIdx.x * blockDim.x + threadIdx.x;
  if (i < n) {
    ns[i] = rsqrtf(fmaxf((float)degO[i], 1.0f));
    nd[i] = rsqrtf(fmaxf((float)degI[i], 1.0f));
  }
}

// ---------------- prefix scan (3-kernel hierarchical) ----------------
__global__ __launch_bounds__(1024) void scan1_kernel(
    const int* __restrict__ deg, int* __restrict__ excl,
    int* __restrict__ blk, int n) {
  __shared__ int lds[1024];
  const int tid = threadIdx.x;
  const int gid = blockIdx.x * 1024 + tid;
  int v = (gid < n) ? deg[gid] : 0;
  lds[tid] = v;
  __syncthreads();
  for (int off = 1; off < 1024; off <<= 1) {
    int t = (tid >= off) ? lds[tid - off] : 0;
    __syncthreads();
    lds[tid] += t;
    __syncthreads();
  }
  if (gid < n) excl[gid] = lds[tid] - v;
  if (tid == 1023) blk[blockIdx.x] = lds[1023];
}

__global__ __launch_bounds__(128) void scan2_kernel(int* __restrict__ blk, int nblk) {
  __shared__ int lds[128];
  const int tid = threadIdx.x;
  int v = (tid < nblk) ? blk[tid] : 0;
  lds[tid] = v;
  __syncthreads();
  for (int off = 1; off < 128; off <<= 1) {
    int t = (tid >= off) ? lds[tid - off] : 0;
    __syncthreads();
    lds[tid] += t;
    __syncthreads();
  }
  if (tid < nblk) blk[tid] = lds[tid] - v;
}

__global__ __launch_bounds__(1024) void scan3_kernel(
    int* __restrict__ row_off, const int* __restrict__ blk,
    int* __restrict__ cursor, int n, int nE) {
  int gid = blockIdx.x * 1024 + threadIdx.x;
  if (gid < n) {
    int v = row_off[gid] + blk[gid >> 10];
    row_off[gid] = v;
    cursor[gid] = v;
  }
  if (gid == 0) row_off[n] = nE;
}

// ---------------- CSR build: scatter src ids by dst ----------------
__global__ __launch_bounds__(256) void scatter_kernel(
    const int* __restrict__ src, const int* __restrict__ dst,
    int* __restrict__ cursor, int* __restrict__ col, int nE) {
  int i = blockIdx.x * blockDim.x + threadIdx.x;
  int stride = gridDim.x * blockDim.x;
  for (int e = i; e < nE; e += stride) {
    int pos = atomicAdd(&cursor[dst[e]], 1);
    col[pos] = src[e];
  }
}

// ---------------- CSR gather aggregation: out[d] = sum_{s in in(d)} x[s]*ns[s] ----------------
// one wave per dst node, 2 floats/lane; ns==nullptr -> no scale (input pre-scaled)
__global__ __launch_bounds__(256) void agg_csr_kernel(
    const float* __restrict__ x, const int* __restrict__ col,
    const int* __restrict__ row_off, const float* __restrict__ ns,
    float* __restrict__ out, int nN) {
  const int wid = (blockIdx.x * blockDim.x + threadIdx.x) >> 6;
  const int lane = threadIdx.x & 63;
  if (wid >= nN) return;
  const int beg = row_off[wid];
  const int end = row_off[wid + 1];
  float ax = 0.0f, ay = 0.0f;
  for (int i0 = beg; i0 < end; i0 += 64) {
    const int cnt = min(64, end - i0);
    int myc = (lane < cnt) ? col[i0 + lane] : 0;
    for (int j = 0; j < cnt; ++j) {
      int s = __shfl(myc, j);
      float sc = ns ? ns[s] : 1.0f;
      float2 v = *reinterpret_cast<const float2*>(x + (size_t)s * 128 + lane * 2);
      ax = fmaf(v.x, sc, ax);
      ay = fmaf(v.y, sc, ay);
    }
  }
  float2 r;
  r.x = ax;
  r.y = ay;
  *reinterpret_cast<float2*>(out + (size_t)wid * 128 + lane * 2) = r;
}

// ---------------- fallback: atomic aggregation (pre-zeroed out) ----------------
__global__ __launch_bounds__(256) void agg_atomic_kernel(
    const float* __restrict__ x, const int* __restrict__ src,
    const int* __restrict__ dst, const float* __restrict__ ns,
    float* __restrict__ out, int nE) {
  int wid = (blockIdx.x * blockDim.x + threadIdx.x) >> 6;
  int lane = threadIdx.x & 63;
  int nwaves = (gridDim.x * blockDim.x) >> 6;
  for (int e = wid; e < nE; e += nwaves) {
    int s = src[e];
    int d = dst[e];
    float sc = ns ? ns[s] : 1.0f;
    float2 v = *reinterpret_cast<const float2*>(x + (size_t)s * 128 + lane * 2);
    float* o = out + (size_t)d * 128 + lane * 2;
    atomicAdd(o, v.x * sc);
    atomicAdd(o + 1, v.y * sc);
  }
}

// ---------------- C = (A * rowscale) @ W + bias, optional postscale; in-place safe ----------------
template <int K, int COLS, int TM, bool RELU>
__global__ __launch_bounds__(256) void gemm_kernel(
    const float* __restrict__ A, const float* __restrict__ rowscale,
    const float* __restrict__ W, const float* __restrict__ bias,
    float* __restrict__ C, const float* __restrict__ postscale) {
  constexpr int RG = 256 / COLS;
  constexpr int RPT = TM / RG;
  __shared__ float a_lds[TM * K];
  const int row0 = blockIdx.x * TM;
  const int tid = threadIdx.x;

  constexpr int NV4 = TM * K / 4;
  for (int i = tid; i < NV4; i += 256) {
    int r = (i * 4) / K;
    float4 v = *reinterpret_cast<const float4*>(A + (size_t)(row0 + r) * K + (i * 4) % K);
    float sc = rowscale ? rowscale[row0 + r] : 1.0f;
    v.x *= sc; v.y *= sc; v.z *= sc; v.w *= sc;
    *reinterpret_cast<float4*>(&a_lds[i * 4]) = v;
  }
  __syncthreads();

  const int col = tid % COLS;
  const int rg = tid / COLS;
  float acc[RPT] = {};
  for (int k0 = 0; k0 < K; k0 += 4) {
    float w0 = W[(size_t)(k0 + 0) * COLS + col];
    float w1 = W[(size_t)(k0 + 1) * COLS + col];
    float w2 = W[(size_t)(k0 + 2) * COLS + col];
    float w3 = W[(size_t)(k0 + 3) * COLS + col];
#pragma unroll
    for (int j = 0; j < RPT; ++j) {
      int r = rg * RPT + j;
      float4 a = *reinterpret_cast<const float4*>(&a_lds[r * K + k0]);
      acc[j] = fmaf(a.x, w0, acc[j]);
      acc[j] = fmaf(a.y, w1, acc[j]);
      acc[j] = fmaf(a.z, w2, acc[j]);
      acc[j] = fmaf(a.w, w3, acc[j]);
    }
  }
  float bv = bias[col];
#pragma unroll
  for (int j = 0; j < RPT; ++j) {
    int r = row0 + rg * RPT + j;
    float v = acc[j] + bv;
    if (RELU) v = fmaxf(v, 0.0f);
    if (postscale) v *= postscale[r];
    C[(size_t)r * COLS + col] = v;
  }
}

// ---------------- fused MLP + proj ----------------
__global__ __launch_bounds__(256) void mlp_kernel(
    const float* __restrict__ H, const float* __restrict__ W3,
    const float* __restrict__ b3, const float* __restrict__ W4,
    const float* __restrict__ b4, float* __restrict__ Out) {
  constexpr int TM = 32;
  __shared__ float h_lds[TM * 128];
  __shared__ float z_lds[TM * 256];
  const int row0 = blockIdx.x * TM;
  const int tid = threadIdx.x;

  for (int i = tid; i < TM * 128 / 4; i += 256) {
    *reinterpret_cast<float4*>(&h_lds[i * 4]) =
        *reinterpret_cast<const float4*>(H + (size_t)row0 * 128 + i * 4);
  }
  __syncthreads();

  {
    const int col = tid;
    float acc[TM] = {};
    for (int k0 = 0; k0 < 128; k0 += 4) {
      float w0 = W3[(size_t)(k0 + 0) * 256 + col];
      float w1 = W3[(size_t)(k0 + 1) * 256 + col];
      float w2 = W3[(size_t)(k0 + 2) * 256 + col];
      float w3v = W3[(size_t)(k0 + 3) * 256 + col];
#pragma unroll
      for (int r = 0; r < TM; ++r) {
        float4 a = *reinterpret_cast<const float4*>(&h_lds[r * 128 + k0]);
        acc[r] = fmaf(a.x, w0, acc[r]);
        acc[r] = fmaf(a.y, w1, acc[r]);
        acc[r] = fmaf(a.z, w2, acc[r]);
        acc[r] = fmaf(a.w, w3v, acc[r]);
      }
    }
    float bv = b3[col];
#pragma unroll
    for (int r = 0; r < TM; ++r)
      z_lds[r * 256 + col] = fmaxf(acc[r] + bv, 0.0f);
  }
  __syncthreads();

  const int col = tid % 64;
  const int rg = tid / 64;
  float yv[8];
  {
    float acc[8] = {};
    for (int k0 = 0; k0 < 256; k0 += 4) {
      float w0 = W4[(size_t)(k0 + 0) * 64 + col];
      float w1 = W4[(size_t)(k0 + 1) * 64 + col];
      float w2 = W4[(size_t)(k0 + 2) * 64 + col];
      float w3v = W4[(size_t)(k0 + 3) * 64 + col];
#pragma unroll
      for (int j = 0; j < 8; ++j) {
        int r = rg * 8 + j;
        float4 a = *reinterpret_cast<const float4*>(&z_lds[r * 256 + k0]);
        acc[j] = fmaf(a.x, w0, acc[j]);
        acc[j] = fmaf(a.y, w1, acc[j]);
        acc[j] = fmaf(a.z, w2, acc[j]);
        acc[j] = fmaf(a.w, w3v, acc[j]);
      }
    }
    float bv = b4[col];
#pragma unroll
    for (int j = 0; j < 8; ++j) yv[j] = acc[j] + bv;
  }

#pragma unroll
  for (int j = 0; j < 8; ++j) h_lds[(rg * 8 + j) * 64 + col] = yv[j];
  __syncthreads();
  {
    const int r = tid / 8;
    const int seg = tid % 8;
    float ss = 0.0f;
#pragma unroll
    for (int j = 0; j < 8; ++j) {
      float v = h_lds[r * 64 + seg * 8 + j];
      ss = fmaf(v, v, ss);
    }
    ss += __shfl_xor(ss, 1);
    ss += __shfl_xor(ss, 2);
    ss += __shfl_xor(ss, 4);
    float rinv = rsqrtf(ss);
#pragma unroll
    for (int j = 0; j < 8; ++j) {
      float v = fabsf(h_lds[r * 64 + seg * 8 + j]) * rinv;
      Out[(size_t)(row0 + r) * 64 + seg * 8 + j] = fmaxf(1e-6f, v);
    }
  }
}

extern "C" void kernel_launch(void* const* d_in, const int* in_sizes, int n_in,
                              void* d_out, int out_size, void* d_ws, size_t ws_size,
                              hipStream_t stream) {
  const float* feat = (const float*)d_in[0];
  const int* src = (const int*)d_in[1];
  const int* dst = (const int*)d_in[2];
  const float* W1 = (const float*)d_in[3];
  const float* b1 = (const float*)d_in[4];
  const float* W2 = (const float*)d_in[5];
  const float* b2 = (const float*)d_in[6];
  const float* W3 = (const float*)d_in[7];
  const float* b3 = (const float*)d_in[8];
  const float* W4 = (const float*)d_in[9];
  const float* b4 = (const float*)d_in[10];
  float* out = (float*)d_out;

  char* ws = (char*)d_ws;
  size_t off = 0;
  auto alloc = [&](size_t bytes) {
    size_t p = off;
    off = (off + bytes + 255) & ~(size_t)255;
    return p;
  };
  float* ns = (float*)(ws + alloc((size_t)NN * 4));
  float* nd = (float*)(ws + alloc((size_t)NN * 4));
  size_t base_small = off;

  // CSR layout
  int* row_off = (int*)(ws + alloc((size_t)(NN + 64) * 4));
  int* col = (int*)(ws + alloc((size_t)NE * 4));
  float* X = (float*)(ws + alloc((size_t)NN * 128 * 4));
  float* Y = (float*)(ws + alloc((size_t)NN * 128 * 4));
  const bool use_csr = (off <= ws_size);

  if (use_csr) {
    // build temps live in X region (X not yet needed)
    int* degO = (int*)X;
    int* degI = degO + NN;
    int* cursor = degI + NN;
    int* blk = cursor + NN;  // 128 ints

    hipMemsetAsync(degO, 0, 2 * (size_t)NN * 4, stream);
    degi_kernel<<<2048, 256, 0, stream>>>(src, dst, degO, degI, NE);
    normi_kernel<<<(NN + 255) / 256, 256, 0, stream>>>(degO, degI, ns, nd, NN);
    const int nblk = (NN + 1023) / 1024;  // 98
    scan1_kernel<<<nblk, 1024, 0, stream>>>(degI, row_off, blk, NN);
    scan2_kernel<<<1, 128, 0, stream>>>(blk, nblk);
    scan3_kernel<<<nblk, 1024, 0, stream>>>(row_off, blk, cursor, NN, NE);
    scatter_kernel<<<2048, 256, 0, stream>>>(src, dst, cursor, col, NE);

    const int aggBlocks = (NN * 64 + 255) / 256;  // 25000
    // layer 1: X = agg(feat, ns); X = ((X*nd)@W1 + b1) * ns   (pre-scale for layer 2)
    agg_csr_kernel<<<aggBlocks, 256, 0, stream>>>(feat, col, row_off, ns, X, NN);
    gemm_kernel<128, 128, 32, false><<<NN / 32, 256, 0, stream>>>(X, nd, W1, b1, X, ns);
    // layer 2: Y = agg(X); Y = (Y*nd)@W2 + b2
    agg_csr_kernel<<<aggBlocks, 256, 0, stream>>>(X, col, row_off, nullptr, Y, NN);
    gemm_kernel<128, 128, 32, false><<<NN / 32, 256, 0, stream>>>(Y, nd, W2, b2, Y, nullptr);

    mlp_kernel<<<NN / 32, 256, 0, stream>>>(Y, W3, b3, W4, b4, out);
  } else {
    // fallback: atomic aggregation, no CSR arrays
    off = base_small;
    float* Xf = (float*)(ws + alloc((size_t)NN * 128 * 4));
    float* Yf = (float*)(ws + alloc((size_t)NN * 128 * 4));
    int* degO = (int*)Xf;
    int* degI = degO + NN;

    hipMemsetAsync(degO, 0, 2 * (size_t)NN * 4, stream);
    degi_kernel<<<2048, 256, 0, stream>>>(src, dst, degO, degI, NE);
    normi_kernel<<<(NN + 255) / 256, 256, 0, stream>>>(degO, degI, ns, nd, NN);

    hipMemsetAsync(Xf, 0, (size_t)NN * 128 * 4, stream);
    agg_atomic_kernel<<<2048, 256, 0, stream>>>(feat, src, dst, ns, Xf, NE);
    gemm_kernel<128, 128, 32, false><<<NN / 32, 256, 0, stream>>>(Xf, nd, W1, b1, Xf, ns);

    hipMemsetAsync(Yf, 0, (size_t)NN * 128 * 4, stream);
    agg_atomic_kernel<<<2048, 256, 0, stream>>>(Xf, src, dst, nullptr, Yf, NE);
    gemm_kernel<128, 128, 32, false><<<NN / 32, 256, 0, stream>>>(Yf, nd, W2, b2, Yf, nullptr);

    mlp_kernel<<<NN / 32, 256, 0, stream>>>(Yf, W3, b3, W4, b4, out);
  }
}

// Round 3
// 651.092 us; speedup vs baseline: 4.9104x; 1.3400x over previous
//
#include <hip/hip_runtime.h>

#define NN 100000
#define NE 1600000

typedef __bf16 bf16x8 __attribute__((ext_vector_type(8)));
typedef float f32x4 __attribute__((ext_vector_type(4)));

static __device__ __forceinline__ float bf2f(unsigned short u) {
  union { unsigned int i; float f; } c;
  c.i = ((unsigned int)u) << 16;
  return c.f;
}
static __device__ __forceinline__ unsigned short f2bf(float f) {
  unsigned int u = __float_as_uint(f);
  unsigned int r = (u + 0x7fff + ((u >> 16) & 1)) >> 16;  // RNE
  return (unsigned short)r;
}

// ---------------- degree accumulation (int atomics) ----------------
__global__ __launch_bounds__(256) void degi_kernel(
    const int* __restrict__ src, const int* __restrict__ dst,
    int* __restrict__ degO, int* __restrict__ degI, int nE) {
  int i = blockIdx.x * blockDim.x + threadIdx.x;
  int stride = gridDim.x * blockDim.x;
  for (int e = i; e < nE; e += stride) {
    atomicAdd(&degO[src[e]], 1);
    atomicAdd(&degI[dst[e]], 1);
  }
}

__global__ __launch_bounds__(256) void normi_kernel(
    const int* __restrict__ degO, const int* __restrict__ degI,
    float* __restrict__ ns, float* __restrict__ nd, int n) {
  int i = blockIdx.x * blockDim.x + threadIdx.x;
  if (i < n) {
    ns[i] = rsqrtf(fmaxf((float)degO[i], 1.0f));
    nd[i] = rsqrtf(fmaxf((float)degI[i], 1.0f));
  }
}

// ---------------- prefix scan ----------------
__global__ __launch_bounds__(1024) void scan1_kernel(
    const int* __restrict__ deg, int* __restrict__ excl,
    int* __restrict__ blk, int n) {
  __shared__ int lds[1024];
  const int tid = threadIdx.x;
  const int gid = blockIdx.x * 1024 + tid;
  int v = (gid < n) ? deg[gid] : 0;
  lds[tid] = v;
  __syncthreads();
  for (int off = 1; off < 1024; off <<= 1) {
    int t = (tid >= off) ? lds[tid - off] : 0;
    __syncthreads();
    lds[tid] += t;
    __syncthreads();
  }
  if (gid < n) excl[gid] = lds[tid] - v;
  if (tid == 1023) blk[blockIdx.x] = lds[1023];
}

__global__ __launch_bounds__(128) void scan2_kernel(int* __restrict__ blk, int nblk) {
  __shared__ int lds[128];
  const int tid = threadIdx.x;
  int v = (tid < nblk) ? blk[tid] : 0;
  lds[tid] = v;
  __syncthreads();
  for (int off = 1; off < 128; off <<= 1) {
    int t = (tid >= off) ? lds[tid - off] : 0;
    __syncthreads();
    lds[tid] += t;
    __syncthreads();
  }
  if (tid < nblk) blk[tid] = lds[tid] - v;
}

__global__ __launch_bounds__(1024) void scan3_kernel(
    int* __restrict__ row_off, const int* __restrict__ blk,
    int* __restrict__ cursor, int n, int nE) {
  int gid = blockIdx.x * 1024 + threadIdx.x;
  if (gid < n) {
    int v = row_off[gid] + blk[gid >> 10];
    row_off[gid] = v;
    cursor[gid] = v;
  }
  if (gid == 0) row_off[n] = nE;
}

__global__ __launch_bounds__(256) void scatter_kernel(
    const int* __restrict__ src, const int* __restrict__ dst,
    int* __restrict__ cursor, int* __restrict__ col, int nE) {
  int i = blockIdx.x * blockDim.x + threadIdx.x;
  int stride = gridDim.x * blockDim.x;
  for (int e = i; e < nE; e += stride) {
    int pos = atomicAdd(&cursor[dst[e]], 1);
    col[pos] = src[e];
  }
}

// ---------------- weight transpose+convert: Wt[c][k] = bf16(W[k][c]) ----------------
__global__ __launch_bounds__(256) void wconv_kernel(
    const float* __restrict__ W, unsigned short* __restrict__ Wt, int K, int C) {
  int i = blockIdx.x * blockDim.x + threadIdx.x;
  if (i >= K * C) return;
  int c = i % C, k = i / C;
  Wt[(size_t)c * K + k] = f2bf(W[i]);
}

// ---------------- prescale: out = bf16(feat * ns[row]) ----------------
__global__ __launch_bounds__(256) void prescale_kernel(
    const float* __restrict__ feat, const float* __restrict__ ns,
    unsigned short* __restrict__ out) {
  int idx = blockIdx.x * blockDim.x + threadIdx.x;  // one per 8 elems
  if (idx >= NN * 16) return;
  int row = idx >> 4;
  int c8 = (idx & 15) * 8;
  float sc = ns[row];
  float4 v0 = *reinterpret_cast<const float4*>(feat + (size_t)row * 128 + c8);
  float4 v1 = *reinterpret_cast<const float4*>(feat + (size_t)row * 128 + c8 + 4);
  union { unsigned short u[8]; uint4 v; } p;
  p.u[0] = f2bf(v0.x * sc); p.u[1] = f2bf(v0.y * sc);
  p.u[2] = f2bf(v0.z * sc); p.u[3] = f2bf(v0.w * sc);
  p.u[4] = f2bf(v1.x * sc); p.u[5] = f2bf(v1.y * sc);
  p.u[6] = f2bf(v1.z * sc); p.u[7] = f2bf(v1.w * sc);
  *reinterpret_cast<uint4*>(out + (size_t)row * 128 + c8) = p.v;
}

// ---------------- CSR gather: out[d] = bf16(nd[d] * sum x[s]) ----------------
__global__ __launch_bounds__(256) void agg_bf16_kernel(
    const unsigned short* __restrict__ x, const int* __restrict__ col,
    const int* __restrict__ row_off, const float* __restrict__ nd,
    unsigned short* __restrict__ out, int nN) {
  const int wid = (blockIdx.x * blockDim.x + threadIdx.x) >> 6;
  const int lane = threadIdx.x & 63;
  if (wid >= nN) return;
  const int beg = row_off[wid];
  const int end = row_off[wid + 1];
  float ax = 0.0f, ay = 0.0f;
  for (int i0 = beg; i0 < end; i0 += 64) {
    const int cnt = min(64, end - i0);
    int myc = (lane < cnt) ? col[i0 + lane] : 0;
    for (int j = 0; j < cnt; ++j) {
      int s = __shfl(myc, j);
      unsigned int v = *reinterpret_cast<const unsigned int*>(x + (size_t)s * 128 + lane * 2);
      ax += bf2f((unsigned short)(v & 0xffffu));
      ay += bf2f((unsigned short)(v >> 16));
    }
  }
  float sc = nd[wid];
  unsigned int r = ((unsigned int)f2bf(ay * sc) << 16) | (unsigned int)f2bf(ax * sc);
  *reinterpret_cast<unsigned int*>(out + (size_t)wid * 128 + lane * 2) = r;
}

// ---------------- MFMA GEMM: C = bf16((A @ W + b) * postscale) ----------------
// A:[nrows,K] bf16, Wt:[COLS,K] bf16 (transposed), 64 rows/block, 4 waves
template <int K, int COLS>
__global__ __launch_bounds__(256) void gemm_mfma_kernel(
    const unsigned short* __restrict__ A, const unsigned short* __restrict__ Wt,
    const float* __restrict__ bias, const float* __restrict__ postscale,
    unsigned short* __restrict__ C, int nrows) {
  constexpr int TM = 64;
  constexpr int NT = COLS / 16;
  constexpr int KS = K / 32;
  __shared__ unsigned short a_lds[TM * K];
  const int row0 = blockIdx.x * TM;
  const int tid = threadIdx.x;
  const int wave = tid >> 6, lane = tid & 63;

  // stage A tile (swizzled)
  constexpr int CHUNKS = TM * K * 2 / 16;
  for (int i = tid; i < CHUNKS; i += 256) {
    int byte_lin = i * 16;
    int r = byte_lin / (K * 2);
    int swz = byte_lin ^ ((r & 7) << 4);
    uint4 v = {0u, 0u, 0u, 0u};
    int gr = row0 + r;
    if (gr < nrows)
      v = *reinterpret_cast<const uint4*>(A + (size_t)gr * K + (byte_lin % (K * 2)) / 2);
    *reinterpret_cast<uint4*>((char*)a_lds + swz) = v;
  }
  __syncthreads();

  const int rrow = wave * 16 + (lane & 15);
  const int kofs = (lane >> 4) * 8;
  f32x4 acc[NT];
#pragma unroll
  for (int nt = 0; nt < NT; ++nt) acc[nt] = f32x4{0.f, 0.f, 0.f, 0.f};

  for (int ks = 0; ks < KS; ++ks) {
    const int k0 = ks * 32;
    int abyte = ((rrow * K + k0 + kofs) * 2) ^ ((rrow & 7) << 4);
    bf16x8 a = *reinterpret_cast<const bf16x8*>((const char*)a_lds + abyte);
#pragma unroll
    for (int nt = 0; nt < NT; ++nt) {
      int c = nt * 16 + (lane & 15);
      bf16x8 b = *reinterpret_cast<const bf16x8*>(Wt + (size_t)c * K + k0 + kofs);
      acc[nt] = __builtin_amdgcn_mfma_f32_16x16x32_bf16(a, b, acc[nt], 0, 0, 0);
    }
  }

  // epilogue via LDS bounce for coalesced bf16 stores
  __syncthreads();
#pragma unroll
  for (int nt = 0; nt < NT; ++nt) {
    int c = nt * 16 + (lane & 15);
    float bv = bias[c];
#pragma unroll
    for (int r = 0; r < 4; ++r) {
      int lrow = wave * 16 + (lane >> 4) * 4 + r;
      int grow = row0 + lrow;
      float ps = (postscale != nullptr && grow < nrows) ? postscale[grow] : 1.0f;
      float v = (acc[nt][r] + bv) * ps;
      a_lds[lrow * COLS + c] = f2bf(v);
    }
  }
  __syncthreads();
  constexpr int OCH = TM * COLS * 2 / 16;
  for (int i = tid; i < OCH; i += 256) {
    int byte_lin = i * 16;
    int r = byte_lin / (COLS * 2);
    int gr = row0 + r;
    if (gr < nrows)
      *reinterpret_cast<uint4*>(C + (size_t)gr * COLS + (byte_lin % (COLS * 2)) / 2) =
          *reinterpret_cast<const uint4*>((const char*)a_lds + byte_lin);
  }
}

// ---------------- fused MLP + proj (MFMA) ----------------
// H:[nrows,128] bf16 -> z=relu(H@W3+b3):[*,256] (LDS) -> y=z@W4+b4 -> proj -> Out f32
__global__ __launch_bounds__(256) void mlp_mfma_kernel(
    const unsigned short* __restrict__ H, const unsigned short* __restrict__ Wt3,
    const float* __restrict__ b3, const unsigned short* __restrict__ Wt4,
    const float* __restrict__ b4, float* __restrict__ Out, int nrows) {
  constexpr int TM = 64;
  __shared__ unsigned short h_lds[TM * 128];   // 16KB swizzled
  __shared__ unsigned short z_lds[TM * 256];   // 32KB swizzled
  const int row0 = blockIdx.x * TM;
  const int tid = threadIdx.x;
  const int wave = tid >> 6, lane = tid & 63;
  const int l15 = lane & 15;
  const int kofs = (lane >> 4) * 8;

  // stage H (swizzled, row stride 256B)
  for (int i = tid; i < TM * 128 * 2 / 16; i += 256) {
    int byte_lin = i * 16;
    int r = byte_lin / 256;
    int swz = byte_lin ^ ((r & 7) << 4);
    uint4 v = {0u, 0u, 0u, 0u};
    int gr = row0 + r;
    if (gr < nrows)
      v = *reinterpret_cast<const uint4*>(H + (size_t)gr * 128 + (byte_lin % 256) / 2);
    *reinterpret_cast<uint4*>((char*)h_lds + swz) = v;
  }
  __syncthreads();

  const int rrow = wave * 16 + l15;
  // phase 1: z = relu(H @ W3 + b3), 16 n-tiles
  {
    f32x4 acc[16];
#pragma unroll
    for (int nt = 0; nt < 16; ++nt) acc[nt] = f32x4{0.f, 0.f, 0.f, 0.f};
    for (int ks = 0; ks < 4; ++ks) {
      const int k0 = ks * 32;
      int abyte = ((rrow * 128 + k0 + kofs) * 2) ^ ((rrow & 7) << 4);
      bf16x8 a = *reinterpret_cast<const bf16x8*>((const char*)h_lds + abyte);
#pragma unroll
      for (int nt = 0; nt < 16; ++nt) {
        int c = nt * 16 + l15;
        bf16x8 b = *reinterpret_cast<const bf16x8*>(Wt3 + (size_t)c * 128 + k0 + kofs);
        acc[nt] = __builtin_amdgcn_mfma_f32_16x16x32_bf16(a, b, acc[nt], 0, 0, 0);
      }
    }
    // write z to LDS (bf16, swizzled, row stride 512B)
#pragma unroll
    for (int nt = 0; nt < 16; ++nt) {
      int c = nt * 16 + l15;
      float bv = b3[c];
#pragma unroll
      for (int r = 0; r < 4; ++r) {
        int lrow = wave * 16 + (lane >> 4) * 4 + r;
        float v = fmaxf(acc[nt][r] + bv, 0.0f);
        int zb = (lrow * 512 + c * 2) ^ ((lrow & 7) << 4);
        *reinterpret_cast<unsigned short*>((char*)z_lds + zb) = f2bf(v);
      }
    }
  }
  __syncthreads();

  // phase 2: y = z @ W4 + b4 (K=256, 4 n-tiles), then proj
  f32x4 acc2[4];
#pragma unroll
  for (int nt = 0; nt < 4; ++nt) acc2[nt] = f32x4{0.f, 0.f, 0.f, 0.f};
  for (int ks = 0; ks < 8; ++ks) {
    const int k0 = ks * 32;
    int zbyte = ((rrow * 256 + k0 + kofs) * 2) ^ ((rrow & 7) << 4);
    bf16x8 a = *reinterpret_cast<const bf16x8*>((const char*)z_lds + zbyte);
#pragma unroll
    for (int nt = 0; nt < 4; ++nt) {
      int c = nt * 16 + l15;
      bf16x8 b = *reinterpret_cast<const bf16x8*>(Wt4 + (size_t)c * 256 + k0 + kofs);
      acc2[nt] = __builtin_amdgcn_mfma_f32_16x16x32_bf16(a, b, acc2[nt], 0, 0, 0);
    }
  }
#pragma unroll
  for (int nt = 0; nt < 4; ++nt) {
    float bv = b4[nt * 16 + l15];
#pragma unroll
    for (int r = 0; r < 4; ++r) acc2[nt][r] += bv;
  }

  // row-wise L2 norm: row = wave*16 + (lane>>4)*4 + r, held across 16 lanes x 4 nt
  float rinv[4];
#pragma unroll
  for (int r = 0; r < 4; ++r) {
    float ss = 0.0f;
#pragma unroll
    for (int nt = 0; nt < 4; ++nt) ss = fmaf(acc2[nt][r], acc2[nt][r], ss);
    ss += __shfl_xor(ss, 1);
    ss += __shfl_xor(ss, 2);
    ss += __shfl_xor(ss, 4);
    ss += __shfl_xor(ss, 8);
    rinv[r] = rsqrtf(ss);
  }
#pragma unroll
  for (int nt = 0; nt < 4; ++nt) {
    int c = nt * 16 + l15;
#pragma unroll
    for (int r = 0; r < 4; ++r) {
      int grow = row0 + wave * 16 + (lane >> 4) * 4 + r;
      if (grow < nrows)
        Out[(size_t)grow * 64 + c] = fmaxf(1e-6f, fabsf(acc2[nt][r]) * rinv[r]);
    }
  }
}

extern "C" void kernel_launch(void* const* d_in, const int* in_sizes, int n_in,
                              void* d_out, int out_size, void* d_ws, size_t ws_size,
                              hipStream_t stream) {
  const float* feat = (const float*)d_in[0];
  const int* src = (const int*)d_in[1];
  const int* dst = (const int*)d_in[2];
  const float* W1 = (const float*)d_in[3];
  const float* b1 = (const float*)d_in[4];
  const float* W2 = (const float*)d_in[5];
  const float* b2 = (const float*)d_in[6];
  const float* W3 = (const float*)d_in[7];
  const float* b3 = (const float*)d_in[8];
  const float* W4 = (const float*)d_in[9];
  const float* b4 = (const float*)d_in[10];
  float* out = (float*)d_out;

  char* ws = (char*)d_ws;
  size_t off = 0;
  auto alloc = [&](size_t bytes) {
    size_t p = off;
    off = (off + bytes + 255) & ~(size_t)255;
    return p;
  };
  float* ns = (float*)(ws + alloc((size_t)NN * 4));
  float* nd = (float*)(ws + alloc((size_t)NN * 4));
  int* row_off = (int*)(ws + alloc((size_t)(NN + 64) * 4));
  int* col = (int*)(ws + alloc((size_t)NE * 4));
  unsigned short* Wt1 = (unsigned short*)(ws + alloc((size_t)128 * 128 * 2));
  unsigned short* Wt2 = (unsigned short*)(ws + alloc((size_t)128 * 128 * 2));
  unsigned short* Wt3 = (unsigned short*)(ws + alloc((size_t)256 * 128 * 2));
  unsigned short* Wt4 = (unsigned short*)(ws + alloc((size_t)64 * 256 * 2));
  unsigned short* B0 = (unsigned short*)(ws + alloc((size_t)NN * 128 * 2));
  unsigned short* B1 = (unsigned short*)(ws + alloc((size_t)NN * 128 * 2));

  // CSR build temps live in B0 (prescale overwrites B0 only after scatter)
  int* degO = (int*)B0;
  int* degI = degO + NN;
  int* cursor = degI + NN;
  int* blk = cursor + NN;  // 128 ints

  hipMemsetAsync(degO, 0, 2 * (size_t)NN * 4, stream);
  degi_kernel<<<2048, 256, 0, stream>>>(src, dst, degO, degI, NE);
  normi_kernel<<<(NN + 255) / 256, 256, 0, stream>>>(degO, degI, ns, nd, NN);
  const int nblk = (NN + 1023) / 1024;  // 98
  scan1_kernel<<<nblk, 1024, 0, stream>>>(degI, row_off, blk, NN);
  scan2_kernel<<<1, 128, 0, stream>>>(blk, nblk);
  scan3_kernel<<<nblk, 1024, 0, stream>>>(row_off, blk, cursor, NN, NE);
  scatter_kernel<<<2048, 256, 0, stream>>>(src, dst, cursor, col, NE);

  // weights -> transposed bf16
  wconv_kernel<<<(128 * 128 + 255) / 256, 256, 0, stream>>>(W1, Wt1, 128, 128);
  wconv_kernel<<<(128 * 128 + 255) / 256, 256, 0, stream>>>(W2, Wt2, 128, 128);
  wconv_kernel<<<(128 * 256 + 255) / 256, 256, 0, stream>>>(W3, Wt3, 128, 256);
  wconv_kernel<<<(256 * 64 + 255) / 256, 256, 0, stream>>>(W4, Wt4, 256, 64);

  const int nGemmBlk = (NN + 63) / 64;
  const int aggBlocks = (NN * 64 + 255) / 256;

  // B0 = bf16(feat * ns)
  prescale_kernel<<<(NN * 16 + 255) / 256, 256, 0, stream>>>(feat, ns, B0);
  // layer 1: B1 = bf16(nd * agg(B0)); B0 = bf16((B1@W1 + b1) * ns)
  agg_bf16_kernel<<<aggBlocks, 256, 0, stream>>>(B0, col, row_off, nd, B1, NN);
  gemm_mfma_kernel<128, 128><<<nGemmBlk, 256, 0, stream>>>(B1, Wt1, b1, ns, B0, NN);
  // layer 2: B1 = bf16(nd * agg(B0)); B0 = bf16(B1@W2 + b2)
  agg_bf16_kernel<<<aggBlocks, 256, 0, stream>>>(B0, col, row_off, nd, B1, NN);
  gemm_mfma_kernel<128, 128><<<nGemmBlk, 256, 0, stream>>>(B1, Wt2, b2, nullptr, B0, NN);
  // MLP + proj
  mlp_mfma_kernel<<<nGemmBlk, 256, 0, stream>>>(B0, Wt3, b3, Wt4, b4, out, NN);
}

// Round 4
// 549.083 us; speedup vs baseline: 5.8227x; 1.1858x over previous
//
#include <hip/hip_runtime.h>

#define NN 100000
#define NE 1600000

typedef __bf16 bf16x8 __attribute__((ext_vector_type(8)));
typedef float f32x4 __attribute__((ext_vector_type(4)));

static __device__ __forceinline__ float bf2f_lo(unsigned int u) {
  return __uint_as_float(u << 16);
}
static __device__ __forceinline__ float bf2f_hi(unsigned int u) {
  return __uint_as_float(u & 0xffff0000u);
}
static __device__ __forceinline__ unsigned short f2bf(float f) {
  unsigned int u = __float_as_uint(f);
  unsigned int r = (u + 0x7fff + ((u >> 16) & 1)) >> 16;  // RNE
  return (unsigned short)r;
}

// ---------------- degree accumulation (int atomics) ----------------
__global__ __launch_bounds__(256) void degi_kernel(
    const int* __restrict__ src, const int* __restrict__ dst,
    int* __restrict__ degO, int* __restrict__ degI, int nE) {
  int i = blockIdx.x * blockDim.x + threadIdx.x;
  int stride = gridDim.x * blockDim.x;
  for (int e = i; e < nE; e += stride) {
    atomicAdd(&degO[src[e]], 1);
    atomicAdd(&degI[dst[e]], 1);
  }
}

__global__ __launch_bounds__(256) void normi_kernel(
    const int* __restrict__ degO, const int* __restrict__ degI,
    float* __restrict__ ns, float* __restrict__ nd, int n) {
  int i = blockIdx.x * blockDim.x + threadIdx.x;
  if (i < n) {
    ns[i] = rsqrtf(fmaxf((float)degO[i], 1.0f));
    nd[i] = rsqrtf(fmaxf((float)degI[i], 1.0f));
  }
}

// ---------------- prefix scan ----------------
__global__ __launch_bounds__(1024) void scan1_kernel(
    const int* __restrict__ deg, int* __restrict__ excl,
    int* __restrict__ blk, int n) {
  __shared__ int lds[1024];
  const int tid = threadIdx.x;
  const int gid = blockIdx.x * 1024 + tid;
  int v = (gid < n) ? deg[gid] : 0;
  lds[tid] = v;
  __syncthreads();
  for (int off = 1; off < 1024; off <<= 1) {
    int t = (tid >= off) ? lds[tid - off] : 0;
    __syncthreads();
    lds[tid] += t;
    __syncthreads();
  }
  if (gid < n) excl[gid] = lds[tid] - v;
  if (tid == 1023) blk[blockIdx.x] = lds[1023];
}

__global__ __launch_bounds__(128) void scan2_kernel(int* __restrict__ blk, int nblk) {
  __shared__ int lds[128];
  const int tid = threadIdx.x;
  int v = (tid < nblk) ? blk[tid] : 0;
  lds[tid] = v;
  __syncthreads();
  for (int off = 1; off < 128; off <<= 1) {
    int t = (tid >= off) ? lds[tid - off] : 0;
    __syncthreads();
    lds[tid] += t;
    __syncthreads();
  }
  if (tid < nblk) blk[tid] = lds[tid] - v;
}

__global__ __launch_bounds__(1024) void scan3_kernel(
    int* __restrict__ row_off, const int* __restrict__ blk,
    int* __restrict__ cursor, int n, int nE) {
  int gid = blockIdx.x * 1024 + threadIdx.x;
  if (gid < n) {
    int v = row_off[gid] + blk[gid >> 10];
    row_off[gid] = v;
    cursor[gid] = v;
  }
  if (gid == 0) row_off[n] = nE;
}

// ---------------- dst-windowed CSR scatter ----------------
// Only edges whose dst falls in [w0,w1) are scattered this pass; keeps the
// col write region (~800KB) + cursor slice L2-resident so lines coalesce.
__global__ __launch_bounds__(256) void scatter_win_kernel(
    const int* __restrict__ src, const int* __restrict__ dst,
    int* __restrict__ cursor, int* __restrict__ col, int nE, int w0, int w1) {
  int i = blockIdx.x * blockDim.x + threadIdx.x;
  int stride = gridDim.x * blockDim.x;
  for (int e = i; e < nE; e += stride) {
    int d = dst[e];
    if (d >= w0 && d < w1) {
      int pos = atomicAdd(&cursor[d], 1);
      col[pos] = src[e];
    }
  }
}

// ---------------- weight transpose+convert: Wt[c][k] = bf16(W[k][c]) ----------------
__global__ __launch_bounds__(256) void wconv_kernel(
    const float* __restrict__ W, unsigned short* __restrict__ Wt, int K, int C) {
  int i = blockIdx.x * blockDim.x + threadIdx.x;
  if (i >= K * C) return;
  int c = i % C, k = i / C;
  Wt[(size_t)c * K + k] = f2bf(W[i]);
}

// ---------------- prescale: out = bf16(feat * ns[row]) ----------------
__global__ __launch_bounds__(256) void prescale_kernel(
    const float* __restrict__ feat, const float* __restrict__ ns,
    unsigned short* __restrict__ out) {
  int idx = blockIdx.x * blockDim.x + threadIdx.x;  // one per 8 elems
  if (idx >= NN * 16) return;
  int row = idx >> 4;
  int c8 = (idx & 15) * 8;
  float sc = ns[row];
  float4 v0 = *reinterpret_cast<const float4*>(feat + (size_t)row * 128 + c8);
  float4 v1 = *reinterpret_cast<const float4*>(feat + (size_t)row * 128 + c8 + 4);
  union { unsigned short u[8]; uint4 v; } p;
  p.u[0] = f2bf(v0.x * sc); p.u[1] = f2bf(v0.y * sc);
  p.u[2] = f2bf(v0.z * sc); p.u[3] = f2bf(v0.w * sc);
  p.u[4] = f2bf(v1.x * sc); p.u[5] = f2bf(v1.y * sc);
  p.u[6] = f2bf(v1.z * sc); p.u[7] = f2bf(v1.w * sc);
  *reinterpret_cast<uint4*>(out + (size_t)row * 128 + c8) = p.v;
}

// ---------------- CSR gather: out[d] = bf16(nd[d] * sum x[s]) ----------------
// one wave per dst node; 4 edges in flight via 16-lane groups, 16B loads/lane
__global__ __launch_bounds__(256) void agg_bf16_kernel(
    const unsigned short* __restrict__ x, const int* __restrict__ col,
    const int* __restrict__ row_off, const float* __restrict__ nd,
    unsigned short* __restrict__ out, int nN) {
  const int wid = (blockIdx.x * blockDim.x + threadIdx.x) >> 6;
  const int lane = threadIdx.x & 63;
  if (wid >= nN) return;
  const int beg = row_off[wid];
  const int end = row_off[wid + 1];
  const int g = lane >> 4;    // edge subgroup 0..3
  const int lg = lane & 15;   // 16B chunk within row

  float acc[8] = {};
  for (int i0 = beg; i0 < end; i0 += 64) {
    const int cnt = min(64, end - i0);
    int myc = (lane < cnt) ? col[i0 + lane] : 0;
    for (int j = 0; j < cnt; j += 4) {
      int idx = j + g;
      int s = __shfl(myc, idx);            // idx>=64 wraps; masked below
      float m = (idx < cnt) ? 1.0f : 0.0f;
      uint4 v = *reinterpret_cast<const uint4*>(x + (size_t)s * 128 + lg * 8);
      acc[0] = fmaf(m, bf2f_lo(v.x), acc[0]);
      acc[1] = fmaf(m, bf2f_hi(v.x), acc[1]);
      acc[2] = fmaf(m, bf2f_lo(v.y), acc[2]);
      acc[3] = fmaf(m, bf2f_hi(v.y), acc[3]);
      acc[4] = fmaf(m, bf2f_lo(v.z), acc[4]);
      acc[5] = fmaf(m, bf2f_hi(v.z), acc[5]);
      acc[6] = fmaf(m, bf2f_lo(v.w), acc[6]);
      acc[7] = fmaf(m, bf2f_hi(v.w), acc[7]);
    }
  }
  // merge the 4 edge subgroups (lanes differing in bits 4,5)
#pragma unroll
  for (int k = 0; k < 8; ++k) {
    acc[k] += __shfl_xor(acc[k], 16);
    acc[k] += __shfl_xor(acc[k], 32);
  }
  if (g == 0) {
    float sc = nd[wid];
    union { unsigned short u[8]; uint4 v; } p;
#pragma unroll
    for (int k = 0; k < 8; ++k) p.u[k] = f2bf(acc[k] * sc);
    *reinterpret_cast<uint4*>(out + (size_t)wid * 128 + lg * 8) = p.v;
  }
}

// ---------------- MFMA GEMM: C = bf16((A @ W + b) * postscale) ----------------
template <int K, int COLS>
__global__ __launch_bounds__(256) void gemm_mfma_kernel(
    const unsigned short* __restrict__ A, const unsigned short* __restrict__ Wt,
    const float* __restrict__ bias, const float* __restrict__ postscale,
    unsigned short* __restrict__ C, int nrows) {
  constexpr int TM = 64;
  constexpr int NT = COLS / 16;
  constexpr int KS = K / 32;
  __shared__ unsigned short a_lds[TM * K];
  const int row0 = blockIdx.x * TM;
  const int tid = threadIdx.x;
  const int wave = tid >> 6, lane = tid & 63;

  constexpr int CHUNKS = TM * K * 2 / 16;
  for (int i = tid; i < CHUNKS; i += 256) {
    int byte_lin = i * 16;
    int r = byte_lin / (K * 2);
    int swz = byte_lin ^ ((r & 7) << 4);
    uint4 v = {0u, 0u, 0u, 0u};
    int gr = row0 + r;
    if (gr < nrows)
      v = *reinterpret_cast<const uint4*>(A + (size_t)gr * K + (byte_lin % (K * 2)) / 2);
    *reinterpret_cast<uint4*>((char*)a_lds + swz) = v;
  }
  __syncthreads();

  const int rrow = wave * 16 + (lane & 15);
  const int kofs = (lane >> 4) * 8;
  f32x4 acc[NT];
#pragma unroll
  for (int nt = 0; nt < NT; ++nt) acc[nt] = f32x4{0.f, 0.f, 0.f, 0.f};

  for (int ks = 0; ks < KS; ++ks) {
    const int k0 = ks * 32;
    int abyte = ((rrow * K + k0 + kofs) * 2) ^ ((rrow & 7) << 4);
    bf16x8 a = *reinterpret_cast<const bf16x8*>((const char*)a_lds + abyte);
#pragma unroll
    for (int nt = 0; nt < NT; ++nt) {
      int c = nt * 16 + (lane & 15);
      bf16x8 b = *reinterpret_cast<const bf16x8*>(Wt + (size_t)c * K + k0 + kofs);
      acc[nt] = __builtin_amdgcn_mfma_f32_16x16x32_bf16(a, b, acc[nt], 0, 0, 0);
    }
  }

  __syncthreads();
#pragma unroll
  for (int nt = 0; nt < NT; ++nt) {
    int c = nt * 16 + (lane & 15);
    float bv = bias[c];
#pragma unroll
    for (int r = 0; r < 4; ++r) {
      int lrow = wave * 16 + (lane >> 4) * 4 + r;
      int grow = row0 + lrow;
      float ps = (postscale != nullptr && grow < nrows) ? postscale[grow] : 1.0f;
      float v = (acc[nt][r] + bv) * ps;
      a_lds[lrow * COLS + c] = f2bf(v);
    }
  }
  __syncthreads();
  constexpr int OCH = TM * COLS * 2 / 16;
  for (int i = tid; i < OCH; i += 256) {
    int byte_lin = i * 16;
    int r = byte_lin / (COLS * 2);
    int gr = row0 + r;
    if (gr < nrows)
      *reinterpret_cast<uint4*>(C + (size_t)gr * COLS + (byte_lin % (COLS * 2)) / 2) =
          *reinterpret_cast<const uint4*>((const char*)a_lds + byte_lin);
  }
}

// ---------------- fused MLP + proj (MFMA) ----------------
__global__ __launch_bounds__(256) void mlp_mfma_kernel(
    const unsigned short* __restrict__ H, const unsigned short* __restrict__ Wt3,
    const float* __restrict__ b3, const unsigned short* __restrict__ Wt4,
    const float* __restrict__ b4, float* __restrict__ Out, int nrows) {
  constexpr int TM = 64;
  __shared__ unsigned short h_lds[TM * 128];
  __shared__ unsigned short z_lds[TM * 256];
  const int row0 = blockIdx.x * TM;
  const int tid = threadIdx.x;
  const int wave = tid >> 6, lane = tid & 63;
  const int l15 = lane & 15;
  const int kofs = (lane >> 4) * 8;

  for (int i = tid; i < TM * 128 * 2 / 16; i += 256) {
    int byte_lin = i * 16;
    int r = byte_lin / 256;
    int swz = byte_lin ^ ((r & 7) << 4);
    uint4 v = {0u, 0u, 0u, 0u};
    int gr = row0 + r;
    if (gr < nrows)
      v = *reinterpret_cast<const uint4*>(H + (size_t)gr * 128 + (byte_lin % 256) / 2);
    *reinterpret_cast<uint4*>((char*)h_lds + swz) = v;
  }
  __syncthreads();

  const int rrow = wave * 16 + l15;
  {
    f32x4 acc[16];
#pragma unroll
    for (int nt = 0; nt < 16; ++nt) acc[nt] = f32x4{0.f, 0.f, 0.f, 0.f};
    for (int ks = 0; ks < 4; ++ks) {
      const int k0 = ks * 32;
      int abyte = ((rrow * 128 + k0 + kofs) * 2) ^ ((rrow & 7) << 4);
      bf16x8 a = *reinterpret_cast<const bf16x8*>((const char*)h_lds + abyte);
#pragma unroll
      for (int nt = 0; nt < 16; ++nt) {
        int c = nt * 16 + l15;
        bf16x8 b = *reinterpret_cast<const bf16x8*>(Wt3 + (size_t)c * 128 + k0 + kofs);
        acc[nt] = __builtin_amdgcn_mfma_f32_16x16x32_bf16(a, b, acc[nt], 0, 0, 0);
      }
    }
#pragma unroll
    for (int nt = 0; nt < 16; ++nt) {
      int c = nt * 16 + l15;
      float bv = b3[c];
#pragma unroll
      for (int r = 0; r < 4; ++r) {
        int lrow = wave * 16 + (lane >> 4) * 4 + r;
        float v = fmaxf(acc[nt][r] + bv, 0.0f);
        int zb = (lrow * 512 + c * 2) ^ ((lrow & 7) << 4);
        *reinterpret_cast<unsigned short*>((char*)z_lds + zb) = f2bf(v);
      }
    }
  }
  __syncthreads();

  f32x4 acc2[4];
#pragma unroll
  for (int nt = 0; nt < 4; ++nt) acc2[nt] = f32x4{0.f, 0.f, 0.f, 0.f};
  for (int ks = 0; ks < 8; ++ks) {
    const int k0 = ks * 32;
    int zbyte = ((rrow * 256 + k0 + kofs) * 2) ^ ((rrow & 7) << 4);
    bf16x8 a = *reinterpret_cast<const bf16x8*>((const char*)z_lds + zbyte);
#pragma unroll
    for (int nt = 0; nt < 4; ++nt) {
      int c = nt * 16 + l15;
      bf16x8 b = *reinterpret_cast<const bf16x8*>(Wt4 + (size_t)c * 256 + k0 + kofs);
      acc2[nt] = __builtin_amdgcn_mfma_f32_16x16x32_bf16(a, b, acc2[nt], 0, 0, 0);
    }
  }
#pragma unroll
  for (int nt = 0; nt < 4; ++nt) {
    float bv = b4[nt * 16 + l15];
#pragma unroll
    for (int r = 0; r < 4; ++r) acc2[nt][r] += bv;
  }

  float rinv[4];
#pragma unroll
  for (int r = 0; r < 4; ++r) {
    float ss = 0.0f;
#pragma unroll
    for (int nt = 0; nt < 4; ++nt) ss = fmaf(acc2[nt][r], acc2[nt][r], ss);
    ss += __shfl_xor(ss, 1);
    ss += __shfl_xor(ss, 2);
    ss += __shfl_xor(ss, 4);
    ss += __shfl_xor(ss, 8);
    rinv[r] = rsqrtf(ss);
  }
#pragma unroll
  for (int nt = 0; nt < 4; ++nt) {
    int c = nt * 16 + l15;
#pragma unroll
    for (int r = 0; r < 4; ++r) {
      int grow = row0 + wave * 16 + (lane >> 4) * 4 + r;
      if (grow < nrows)
        Out[(size_t)grow * 64 + c] = fmaxf(1e-6f, fabsf(acc2[nt][r]) * rinv[r]);
    }
  }
}

extern "C" void kernel_launch(void* const* d_in, const int* in_sizes, int n_in,
                              void* d_out, int out_size, void* d_ws, size_t ws_size,
                              hipStream_t stream) {
  const float* feat = (const float*)d_in[0];
  const int* src = (const int*)d_in[1];
  const int* dst = (const int*)d_in[2];
  const float* W1 = (const float*)d_in[3];
  const float* b1 = (const float*)d_in[4];
  const float* W2 = (const float*)d_in[5];
  const float* b2 = (const float*)d_in[6];
  const float* W3 = (const float*)d_in[7];
  const float* b3 = (const float*)d_in[8];
  const float* W4 = (const float*)d_in[9];
  const float* b4 = (const float*)d_in[10];
  float* out = (float*)d_out;

  char* ws = (char*)d_ws;
  size_t off = 0;
  auto alloc = [&](size_t bytes) {
    size_t p = off;
    off = (off + bytes + 255) & ~(size_t)255;
    return p;
  };
  float* ns = (float*)(ws + alloc((size_t)NN * 4));
  float* nd = (float*)(ws + alloc((size_t)NN * 4));
  int* row_off = (int*)(ws + alloc((size_t)(NN + 64) * 4));
  int* col = (int*)(ws + alloc((size_t)NE * 4));
  unsigned short* Wt1 = (unsigned short*)(ws + alloc((size_t)128 * 128 * 2));
  unsigned short* Wt2 = (unsigned short*)(ws + alloc((size_t)128 * 128 * 2));
  unsigned short* Wt3 = (unsigned short*)(ws + alloc((size_t)256 * 128 * 2));
  unsigned short* Wt4 = (unsigned short*)(ws + alloc((size_t)64 * 256 * 2));
  unsigned short* B0 = (unsigned short*)(ws + alloc((size_t)NN * 128 * 2));
  unsigned short* B1 = (unsigned short*)(ws + alloc((size_t)NN * 128 * 2));

  // CSR build temps live in B0 (prescale overwrites B0 only after scatter)
  int* degO = (int*)B0;
  int* degI = degO + NN;
  int* cursor = degI + NN;
  int* blk = cursor + NN;  // 128 ints

  hipMemsetAsync(degO, 0, 2 * (size_t)NN * 4, stream);
  degi_kernel<<<2048, 256, 0, stream>>>(src, dst, degO, degI, NE);
  normi_kernel<<<(NN + 255) / 256, 256, 0, stream>>>(degO, degI, ns, nd, NN);
  const int nblk = (NN + 1023) / 1024;  // 98
  scan1_kernel<<<nblk, 1024, 0, stream>>>(degI, row_off, blk, NN);
  scan2_kernel<<<1, 128, 0, stream>>>(blk, nblk);
  scan3_kernel<<<nblk, 1024, 0, stream>>>(row_off, blk, cursor, NN, NE);

  // dst-windowed scatter: 8 passes, window col region stays L2-resident
  constexpr int NWIN = 8;
  constexpr int WSZ = (NN + NWIN - 1) / NWIN;  // 12500
  for (int w = 0; w < NWIN; ++w) {
    scatter_win_kernel<<<1024, 256, 0, stream>>>(src, dst, cursor, col, NE,
                                                 w * WSZ, min(NN, (w + 1) * WSZ));
  }

  wconv_kernel<<<(128 * 128 + 255) / 256, 256, 0, stream>>>(W1, Wt1, 128, 128);
  wconv_kernel<<<(128 * 128 + 255) / 256, 256, 0, stream>>>(W2, Wt2, 128, 128);
  wconv_kernel<<<(128 * 256 + 255) / 256, 256, 0, stream>>>(W3, Wt3, 128, 256);
  wconv_kernel<<<(256 * 64 + 255) / 256, 256, 0, stream>>>(W4, Wt4, 256, 64);

  const int nGemmBlk = (NN + 63) / 64;
  const int aggBlocks = (NN * 64 + 255) / 256;

  prescale_kernel<<<(NN * 16 + 255) / 256, 256, 0, stream>>>(feat, ns, B0);
  agg_bf16_kernel<<<aggBlocks, 256, 0, stream>>>(B0, col, row_off, nd, B1, NN);
  gemm_mfma_kernel<128, 128><<<nGemmBlk, 256, 0, stream>>>(B1, Wt1, b1, ns, B0, NN);
  agg_bf16_kernel<<<aggBlocks, 256, 0, stream>>>(B0, col, row_off, nd, B1, NN);
  gemm_mfma_kernel<128, 128><<<nGemmBlk, 256, 0, stream>>>(B1, Wt2, b2, nullptr, B0, NN);
  mlp_mfma_kernel<<<nGemmBlk, 256, 0, stream>>>(B0, Wt3, b3, Wt4, b4, out, NN);
}